// Round 4
// baseline (344.736 us; speedup 1.0000x reference)
//
#include <hip/hip_runtime.h>
#include <stdint.h>

// ---------------------------------------------------------------------------
// GCN 2-layer: out = Ahat( dropout(elu( Ahat(x@W1)+b1 )) @ W2 ) + b2
// Ahat = D^-1/2 (A+I) D^-1/2
// dropout = jax threefry2x32 key(42), p=0.25, partitionable path.
// R13->R14: GEMM was concurrency-limited (Little's law): ~3 waves/SIMD grid
// cap + VGPR-bound staging loads -> ~2.3KB in flight/CU -> ~1.3 TB/s. Fix:
//  (a) A staged fp32 via global_load_lds width=16 (fire-and-forget DMA, no
//      dest VGPRs: whole 64KB tile in flight at once). cvt fp32->fp16 moves
//      into the MFMA loop (VALU was 7% idle).
//  (b) 512-thread/8-wave blocks, tile 32x256, wave tile 16x64 (acc = 16
//      VGPRs). Grid 1563x8 = 12500 waves, 2 blocks/CU = 4 waves/SIMD.
//  (c) LDS swizzle per rule 21: linear LDS dest, involution off^=(row&7)<<4
//      applied to per-lane GLOBAL source + same XOR on ds_read -> 2-way
//      bank pattern (free), coalescing preserved (same cache lines).
// ---------------------------------------------------------------------------

typedef float floatx4 __attribute__((ext_vector_type(4)));
typedef _Float16 f16;
typedef _Float16 f16x8 __attribute__((ext_vector_type(8)));

union F16x8 {
  f16x8 v;
  f16 e[8];
  uint4 q;
};

__device__ __forceinline__ void gload_lds16(const void* g, void* l) {
  __builtin_amdgcn_global_load_lds(
      (const __attribute__((address_space(1))) void*)g,
      (__attribute__((address_space(3))) void*)l, 16, 0, 0);
}

// ---------------- Threefry-2x32, key = (0, 42), 20 rounds ------------------
__device__ __forceinline__ void tf_round(uint32_t& x0, uint32_t& x1, int r) {
  x0 += x1;
  x1 = (x1 << r) | (x1 >> (32 - r));
  x1 ^= x0;
}

__device__ __forceinline__ void threefry_0_42(uint32_t c0, uint32_t c1,
                                              uint32_t& o0, uint32_t& o1) {
  const uint32_t ks0 = 0u;
  const uint32_t ks1 = 42u;
  const uint32_t ks2 = 0x1BD11BDAu ^ 0u ^ 42u;
  uint32_t x0 = c0 + ks0;
  uint32_t x1 = c1 + ks1;
  tf_round(x0, x1, 13); tf_round(x0, x1, 15); tf_round(x0, x1, 26); tf_round(x0, x1, 6);
  x0 += ks1; x1 += ks2 + 1u;
  tf_round(x0, x1, 17); tf_round(x0, x1, 29); tf_round(x0, x1, 16); tf_round(x0, x1, 24);
  x0 += ks2; x1 += ks0 + 2u;
  tf_round(x0, x1, 13); tf_round(x0, x1, 15); tf_round(x0, x1, 26); tf_round(x0, x1, 6);
  x0 += ks0; x1 += ks1 + 3u;
  tf_round(x0, x1, 17); tf_round(x0, x1, 29); tf_round(x0, x1, 16); tf_round(x0, x1, 24);
  x0 += ks1; x1 += ks2 + 4u;
  tf_round(x0, x1, 13); tf_round(x0, x1, 15); tf_round(x0, x1, 26); tf_round(x0, x1, 6);
  x0 += ks2; x1 += ks0 + 5u;
  o0 = x0; o1 = x1;
}

// mask byte for features [8b, 8b+8): bit i set = keep (u < 0.75)
__device__ __forceinline__ unsigned char mask_byte(uint32_t b) {
  uint32_t jb = b << 3;
  uint32_t m = 0;
#pragma unroll
  for (int i = 0; i < 8; ++i) {
    uint32_t r0, r1;
    threefry_0_42(0u, jb + (uint32_t)i, r0, r1);
    uint32_t bits = r0 ^ r1;
    // u = bitcast((bits>>9)|0x3f800000)-1 < 0.75  <=>  bits < 0xC0000000 (exact)
    m |= (bits < 0xC0000000u ? 1u : 0u) << i;
  }
  return (unsigned char)m;
}

// ---------------- degree (+ dropout-mask bytes [0,nb0)) --------------------
__global__ void k_deg(const int* __restrict__ dst, int E, int* __restrict__ deg,
                      unsigned char* __restrict__ maskb, int nb0) {
  int t = blockIdx.x * blockDim.x + threadIdx.x;
  if (t < E) atomicAdd(&deg[dst[t]], 1);
  if (t < nb0) maskb[t] = mask_byte((uint32_t)t);
}

// ---------------- 3-phase exclusive scan (+ dinv fused) --------------------
__global__ __launch_bounds__(256) void k_scan1(const int* __restrict__ deg,
                                               int* __restrict__ excl,
                                               int* __restrict__ sums,
                                               float* __restrict__ dinv, int N) {
  __shared__ int sm[256];
  int tid = threadIdx.x;
  int i = blockIdx.x * 256 + tid;
  int v = (i < N) ? deg[i] : 0;
  if (i < N) dinv[i] = 1.0f / sqrtf((float)(v + 1));  // +1 self loop
  sm[tid] = v;
  __syncthreads();
#pragma unroll
  for (int off = 1; off < 256; off <<= 1) {
    int t = (tid >= off) ? sm[tid - off] : 0;
    __syncthreads();
    sm[tid] += t;
    __syncthreads();
  }
  if (i < N) excl[i] = sm[tid] - v;
  if (tid == 255) sums[blockIdx.x] = sm[255];
}

__global__ __launch_bounds__(1024) void k_scan2(int* __restrict__ sums, int nb) {
  __shared__ int sm[1024];
  int tid = threadIdx.x;
  int v = (tid < nb) ? sums[tid] : 0;
  sm[tid] = v;
  __syncthreads();
#pragma unroll
  for (int off = 1; off < 1024; off <<= 1) {
    int t = (tid >= off) ? sm[tid - off] : 0;
    __syncthreads();
    sm[tid] += t;
    __syncthreads();
  }
  if (tid < nb) sums[tid] = sm[tid] - v;  // exclusive, in place
}

__global__ void k_scan3(int* __restrict__ rowptr, int* __restrict__ cursor,
                        const int* __restrict__ sums, int N, int E) {
  int i = blockIdx.x * blockDim.x + threadIdx.x;
  if (i < N) {
    int r = rowptr[i] + sums[i >> 8];
    rowptr[i] = r;
    cursor[i] = r;
  }
  if (i == 0) rowptr[N] = E;
}

// ---------------- bucket edges by dst (+ mask bytes [nb0,nb0+nb1)) ---------
__global__ void k_bucket(const int* __restrict__ src, const int* __restrict__ dst,
                         int* __restrict__ cursor, int* __restrict__ csr_src, int E,
                         unsigned char* __restrict__ maskb, int nb0, int nb1) {
  int t = blockIdx.x * blockDim.x + threadIdx.x;
  if (t < E) {
    int pos = atomicAdd(&cursor[dst[t]], 1);
    csr_src[pos] = src[t];
  }
  if (t < nb1) maskb[nb0 + t] = mask_byte((uint32_t)(nb0 + t));
}

// -------- prep: W1 [512][256] fp32 -> packed fragment-major fp16 -----------
// uint4 entry index = (ks*16 + nt)*64 + lane; 8 fp16 each.
// lane = quad*16 + (n&15), k = ks*32 + quad*8 + j, nt = n>>4.
__global__ void k_prep_w1t(const float* __restrict__ W1,
                           f16* __restrict__ Bpk) {
  int t = blockIdx.x * blockDim.x + threadIdx.x;  // t = k*256+n
  if (t >= 512 * 256) return;
  int k = t >> 8, n = t & 255;
  int ks = k >> 5, quad = (k >> 3) & 3, j = k & 7;
  int nt = n >> 4, lane = quad * 16 + (n & 15);
  size_t e = ((size_t)(ks * 16 + nt)) * 64 + lane;
  Bpk[e * 8 + j] = (f16)W1[t];
}

// -------- GEMM1: hs = (f16) dinv ⊙ (x @ W1), single fp16 MFMA --------------
// Block tile 32 rows x 256 cols, 8 waves (wave = 16 rows x 64 cols).
// A tile (32 x 512 fp32 = 64 KB) staged whole-K via global_load_lds (async
// DMA, no VGPR round trip, all 8 loads/thread in flight), ONE barrier, then
// 16 K-steps barrier-free: B depth-1 register prefetch (L2-hot), A via
// ds_read_b128 x2 + in-loop cvt fp32->fp16, MFMA.
__global__ __launch_bounds__(512, 4) void k_gemm_mfma(
    const float* __restrict__ A,     // [M,512]
    const uint4* __restrict__ Bpk,   // packed fp16, 16384 uint4 (256 KB)
    const float* __restrict__ dinv,  // [M]
    f16* __restrict__ C,             // [M,256] scaled output
    int M) {
  __shared__ char As[32 * 2048];     // 32 rows x 512 fp32, rows linear, 64 KB
  const int tid = threadIdx.x;
  const int wid = tid >> 6;          // 0..7
  const int lane = tid & 63;
  const int quad = lane >> 4;
  const int l16 = lane & 15;
  const int m0 = blockIdx.x * 32;

  // ---- async staging: chunk c = tid + i*512; row = c>>7; 16B chunks -------
  // LDS dest linear (wave-uniform base + lane*16); global source carries the
  // involution off ^= (row&7)<<4 so swizzled reads below see correct data.
#pragma unroll
  for (int i = 0; i < 8; ++i) {
    const int c = tid + i * 512;
    const int row = c >> 7;
    const int off = (c & 127) << 4;
    int grow = m0 + row;
    if (grow >= M) grow = M - 1;
    const char* gsrc = (const char*)(A + (size_t)grow * 512) + (off ^ ((row & 7) << 4));
    char* ldst = As + (size_t)(wid * 64 + i * 512) * 16;  // wave-uniform
    gload_lds16(gsrc, ldst);
  }
  __syncthreads();  // compiler inserts vmcnt(0) drain; the ONLY barrier

  const int wr = wid >> 2;           // row group (0..1)
  const int wc = wid & 3;            // col group (0..3)
  const int R = wr * 16 + l16;       // LDS row for this lane's A fragment
  const int rsw = (R & 7) << 4;      // read-side swizzle

  floatx4 acc[4];                    // [col-tile]
#pragma unroll
  for (int t = 0; t < 4; ++t) acc[t] = (floatx4){0.f, 0.f, 0.f, 0.f};

  const uint4* bp0 = Bpk + lane + (size_t)(wc * 4) * 64;

  union F32x4 { uint4 q; float f[4]; };

  uint4 pb[2][4];                    // B depth-1 register prefetch
#pragma unroll
  for (int t = 0; t < 4; ++t) pb[0][t] = bp0[t * 64];

#pragma unroll
  for (int ks = 0; ks < 16; ++ks) {
    const int cur = ks & 1;
    const int nxt = cur ^ 1;
    if (ks < 15) {
      const uint4* bp = bp0 + (size_t)(ks + 1) * 1024;
#pragma unroll
      for (int t = 0; t < 4; ++t) pb[nxt][t] = bp[t * 64];
    }

    // A fragment: 8 fp32 (32B) from LDS, swizzled, cvt to fp16
    const char* abase = As + R * 2048;
    const int o = ks * 128 + quad * 32;
    F32x4 a0, a1;
    a0.q = *(const uint4*)(abase + ((o) ^ rsw));
    a1.q = *(const uint4*)(abase + ((o + 16) ^ rsw));
    F16x8 af;
    af.e[0] = (f16)a0.f[0]; af.e[1] = (f16)a0.f[1];
    af.e[2] = (f16)a0.f[2]; af.e[3] = (f16)a0.f[3];
    af.e[4] = (f16)a1.f[0]; af.e[5] = (f16)a1.f[1];
    af.e[6] = (f16)a1.f[2]; af.e[7] = (f16)a1.f[3];

#pragma unroll
    for (int t = 0; t < 4; ++t) {
      F16x8 bf;
      bf.q = pb[cur][t];
      acc[t] = __builtin_amdgcn_mfma_f32_16x16x32_f16(af.v, bf.v, acc[t], 0, 0, 0);
    }
  }

  // store hs = dinv[row] * acc; C/D layout col=lane&15, row=quad*4+reg
#pragma unroll
  for (int r = 0; r < 4; ++r) {
    int gm = m0 + wr * 16 + quad * 4 + r;
    if (gm < M) {
      float dv = dinv[gm];
#pragma unroll
      for (int t = 0; t < 4; ++t) {
        const int col = (wc * 4 + t) * 16 + l16;
        C[(size_t)gm * 256 + col] = (f16)(dv * acc[t][r]);
      }
    }
  }
}

// ------- fused gather1 + (+b1 -> elu -> dropout -> dot W2) -----------------
// hs is pre-scaled by dinv. agg[d] = dd*(hs[d] + Σ hs[s]).
// one wave serves TWO nodes (half-wave each); lane covers 8 fp16 feats (16B).
// stores zs[d] = dd * z[d] (pre-scaled for layer-2 gather).
// Accumulation in packed fp16 (v_pk_add_f16); dropout mask from precomputed
// packed-bit table (1.6 MB, L2-hot) instead of in-kernel threefry.
__global__ __launch_bounds__(256) void k_gather_fused(
    const int* __restrict__ rowptr, const int* __restrict__ csr_src,
    const float* __restrict__ dinv, const f16* __restrict__ hs,
    const float* __restrict__ b1, const float* __restrict__ W2,
    const unsigned char* __restrict__ maskb,
    float* __restrict__ zs, int N) {
  int wave = (blockIdx.x * blockDim.x + threadIdx.x) >> 6;
  int lane = threadIdx.x & 63;
  int half = lane >> 5;
  int l = lane & 31;
  int d = wave * 2 + half;
  bool valid = d < N;
  if (!valid) d = N - 1;
  float dd = dinv[d];
  int beg = rowptr[d], end = rowptr[d + 1];
  int f0 = l << 3;  // 8 features per lane

  F16x8 accu;
  accu.q = *(const uint4*)(hs + ((size_t)d << 8) + f0);  // self term
  f16x8 accv = accu.v;

  int e = beg;
  // peel to 16B-aligned csr_src index loads (csr_src is 256B-aligned)
  {
    int pe = beg + ((4 - (beg & 3)) & 3);
    if (pe > end) pe = end;
    for (; e < pe; ++e) {
      F16x8 a;
      a.q = *(const uint4*)(hs + ((size_t)csr_src[e] << 8) + f0);
      accv = accv + a.v;
    }
  }
  for (; e + 3 < end; e += 4) {
    int4 s4 = *(const int4*)(csr_src + e);  // one dwordx4 for 4 indices
    F16x8 a, b, c, dq;
    a.q  = *(const uint4*)(hs + ((size_t)s4.x << 8) + f0);
    b.q  = *(const uint4*)(hs + ((size_t)s4.y << 8) + f0);
    c.q  = *(const uint4*)(hs + ((size_t)s4.z << 8) + f0);
    dq.q = *(const uint4*)(hs + ((size_t)s4.w << 8) + f0);
    f16x8 t0 = a.v + b.v;     // v_pk_add_f16 x4
    f16x8 t1 = c.v + dq.v;
    accv = accv + (t0 + t1);
  }
  for (; e < end; ++e) {
    F16x8 a;
    a.q = *(const uint4*)(hs + ((size_t)csr_src[e] << 8) + f0);
    accv = accv + a.v;
  }
  accu.v = accv;

  // epilogue: scale by dd, bias, elu, masked dropout, dot W2
  float4 bb0 = *(const float4*)(b1 + f0);
  float4 bb1 = *(const float4*)(b1 + f0 + 4);
  float4 w0  = *(const float4*)(W2 + f0);
  float4 w1  = *(const float4*)(W2 + f0 + 4);
  const float* bbp[8] = {&bb0.x, &bb0.y, &bb0.z, &bb0.w, &bb1.x, &bb1.y, &bb1.z, &bb1.w};
  const float* wp[8]  = {&w0.x, &w0.y, &w0.z, &w0.w, &w1.x, &w1.y, &w1.z, &w1.w};

  uint32_t mb = maskb[(size_t)d * 32 + l];  // 8 keep-bits for this lane

  float sum = 0.f;
#pragma unroll
  for (int i = 0; i < 8; ++i) {
    float va = dd * (float)accu.e[i] + *bbp[i];
    float ea = va > 0.f ? va : (__expf(va) - 1.0f);  // elu (fast exp)
    float ha = ((mb >> i) & 1u) ? (ea * (1.0f / 0.75f)) : 0.f;
    sum += ha * *wp[i];
  }
#pragma unroll
  for (int off = 16; off > 0; off >>= 1) sum += __shfl_down(sum, off, 32);
  if (l == 0 && valid) zs[d] = dd * sum;
}

// ------- gather layer 2: out[d] = b2 + dd*(zs[d] + Σ zs[s]) ----------------
// 4 nodes per wave (16 lanes each; avg degree ~16)
__global__ __launch_bounds__(256) void k_gather2(
    const int* __restrict__ rowptr, const int* __restrict__ csr_src,
    const float* __restrict__ dinv, const float* __restrict__ zs,
    const float* __restrict__ b2, float* __restrict__ out, int N) {
  int wave = (blockIdx.x * blockDim.x + threadIdx.x) >> 6;
  int lane = threadIdx.x & 63;
  int sub = lane >> 4;   // 0..3
  int l = lane & 15;
  int d = wave * 4 + sub;
  bool valid = d < N;
  if (!valid) d = N - 1;
  float dd = dinv[d];
  int beg = rowptr[d], end = rowptr[d + 1];

  float acc = 0.f;
  for (int e = beg + l; e < end; e += 16) {
    acc += zs[csr_src[e]];
  }
#pragma unroll
  for (int off = 8; off > 0; off >>= 1) acc += __shfl_down(acc, off, 16);
  if (l == 0 && valid) out[d] = b2[0] + dd * (zs[d] + acc);
}

// ---------------------------------------------------------------------------
extern "C" void kernel_launch(void* const* d_in, const int* in_sizes, int n_in,
                              void* d_out, int out_size, void* d_ws, size_t ws_size,
                              hipStream_t stream) {
  const float* x  = (const float*)d_in[0];
  const int*   ei = (const int*)d_in[1];   // [2,E] int32
  const float* W1 = (const float*)d_in[2];
  const float* b1 = (const float*)d_in[3];
  const float* W2 = (const float*)d_in[4];
  const float* b2 = (const float*)d_in[5];
  float* out = (float*)d_out;

  const int E = in_sizes[1] / 2;
  const int N = in_sizes[0] / 512;  // 50000
  const int* src = ei;
  const int* dst = ei + E;

  char* ws = (char*)d_ws;
  size_t off = 0;
  auto alloc = [&](size_t bytes) -> void* {
    void* p = ws + off;
    off += (bytes + 255) & ~(size_t)255;
    return p;
  };
  int*   deg     = (int*)  alloc((size_t)N * 4);
  int*   rowptr  = (int*)  alloc((size_t)(N + 1) * 4);
  int*   cursor  = (int*)  alloc((size_t)N * 4);
  int*   csr_src = (int*)  alloc((size_t)E * 4);          // 3.2 MB
  int*   sums    = (int*)  alloc(1024 * 4);
  float* dinv    = (float*)alloc((size_t)N * 4);
  f16*   hs      = (f16*)  alloc((size_t)N * 256 * 2);    // 25.6 MB
  float* zs      = (float*)alloc((size_t)N * 4);
  f16*   Bpk     = (f16*)  alloc(512 * 256 * 2);          // 256 KB packed W1
  unsigned char* maskb = (unsigned char*)alloc((size_t)N * 32);  // 1.6 MB mask

  const int nb = (N + 255) / 256;  // scan blocks

  // dropout mask bytes: N*32 total, split across k_deg (first half) and
  // k_bucket (second half) -- both are atomic-latency-bound, VALU idle.
  const int nbytes = N * 32;
  const int nb0 = nbytes >> 1;
  const int nb1 = nbytes - nb0;
  const int tdeg = (E > nb0) ? E : nb0;
  const int tbkt = (E > nb1) ? E : nb1;

  hipMemsetAsync(deg, 0, (size_t)N * 4, stream);
  k_prep_w1t<<<(512 * 256 + 255) / 256, 256, 0, stream>>>(W1, Bpk);
  k_deg<<<(tdeg + 255) / 256, 256, 0, stream>>>(dst, E, deg, maskb, nb0);
  k_scan1<<<nb, 256, 0, stream>>>(deg, rowptr, sums, dinv, N);
  k_scan2<<<1, 1024, 0, stream>>>(sums, nb);
  k_scan3<<<(N + 255) / 256, 256, 0, stream>>>(rowptr, cursor, sums, N, E);
  k_bucket<<<(tbkt + 255) / 256, 256, 0, stream>>>(src, dst, cursor, csr_src, E,
                                                   maskb, nb0, nb1);

  k_gemm_mfma<<<(N + 31) / 32, 512, 0, stream>>>(x, (const uint4*)Bpk, dinv, hs, N);

  const int nwaves1 = (N + 1) / 2;  // 2 nodes per wave
  k_gather_fused<<<(nwaves1 * 64 + 255) / 256, 256, 0, stream>>>(rowptr, csr_src, dinv, hs,
                                                                 b1, W2, maskb, zs, N);
  const int nwaves2 = (N + 3) / 4;  // 4 nodes per wave
  k_gather2<<<(nwaves2 * 64 + 255) / 256, 256, 0, stream>>>(rowptr, csr_src, dinv, zs, b2, out, N);
}